// Round 13
// baseline (199.506 us; speedup 1.0000x reference)
//
#include <hip/hip_runtime.h>
#include <hip/hip_bf16.h>

// out[b,i] = sum_{j<=i} x[b,j] * kernel[i-j]   (causal Toeplitz matmul)
// M=2048, N=K=4096. f32 in/out, bf16 MFMA compute.
//
// R18: fold the A f32->bf16 conversion INTO the gemm; prep shrinks from 4114
// blocks (~9us, 50MB HBM at roofline) to 18 krev-only blocks (~1us).
// Evidence: R13-R17 converge at gemm ~35-36.5us under five different
// schedules (port floor 10.5-21us, matrix 17us) -> not pipe-bound; meanwhile
// prep is pure fixed overhead existing only to pre-convert A. The gemm now
// reads x (f32, row-major, L2-resident panels) directly: per fragment 2x
// global_load_dwordx4/lane + 8 f2bf VALU (VALU idle all session, co-issues
// with MFMA). R17's 256-reg chassis is the only one with headroom: acc 64 +
// af 32 + raw-f32 64 + addr ~200 regs, no spill (R13's 128-reg budget can't
// hold the raw set - that decides the chassis). Raw loads for t+1 issue at
// the top of step t (~1240 SIMD-cyc MFMA cover vs ~300-400 L2 latency),
// convert at step bottom. f2bf bit-identical to prep's -> same numerics.
// wn-dup waves read the same lines within a step -> L1 absorbs the dup, L2
// sees ~540MB as before. B machinery / combine / epilogue: R17 verbatim.

typedef unsigned short u16;
typedef __attribute__((ext_vector_type(8))) short  bf16x8;
typedef __attribute__((ext_vector_type(8))) unsigned short u16x8;
typedef __attribute__((ext_vector_type(4))) float  f32x4;

#define KDIM 4096
#define NDIM 4096
#define MDIM 2048
#define KREV_STRIDE 4608                    // elems per shifted copy (global)
#define KREV_BYTES  (8 * KREV_STRIDE * 2)   // 73728

#define MFMA_BF16 __builtin_amdgcn_mfma_f32_16x16x32_bf16

static __device__ inline u16 f2bf(float f) {
  unsigned u = __builtin_bit_cast(unsigned, f);
  unsigned r = u + 0x7FFFu + ((u >> 16) & 1u);
  return (u16)(r >> 16);
}

static __device__ inline bf16x8 cvt8(f32x4 a, f32x4 b) {
  u16x8 r;
  r[0] = f2bf(a[0]); r[1] = f2bf(a[1]); r[2] = f2bf(a[2]); r[3] = f2bf(a[3]);
  r[4] = f2bf(b[0]); r[5] = f2bf(b[1]); r[6] = f2bf(b[2]); r[7] = f2bf(b[3]);
  return __builtin_bit_cast(bf16x8, r);
}

static __device__ inline void async_copy16(const void* g, void* l) {
  __builtin_amdgcn_global_load_lds((const __attribute__((address_space(1))) void*)g,
                                   (__attribute__((address_space(3))) void*)l,
                                   16, 0, 0);
}

// prep: 18 blocks build 8 shifted krev copies. krevs[a][u] = krev_logical
// [u+a-8]; krev_logical[t] = kern[4095-t] for t in [0,4096) else 0.
__global__ __launch_bounds__(256) void prep(const float* __restrict__ kern,
                                            u16* __restrict__ krevs) {
  int u = (int)blockIdx.x * 256 + threadIdx.x;
  for (int a = 0; a < 8; ++a) {
    int t = u + a - 8;
    u16 v = 0;
    if (t >= 0 && t <= 4095) v = f2bf(kern[4095 - t]);
    krevs[a * KREV_STRIDE + u] = v;
  }
}

__global__ __launch_bounds__(512, 2) void toeplitz_gemm(const float* __restrict__ x,
                                                        const u16* __restrict__ krevs,
                                                        float* __restrict__ out) {
  // LDS: two B windows, 8 copies each, stride_q = 128(ctq+1)+200 elems
  // (==8 mod 64, a*16B bank phase); stride1+stride2 = 4624 -> 73984 B fixed.
  // Phase-1 region (8*stride1*2 >= 38016 B, dead after phase-1 compute)
  // hosts the 36864 B combine overlay; phase-2 region stays intact.
  __shared__ __align__(16) char smem_raw[73984];
  u16*   B_all = (u16*)smem_raw;
  f32x4* ep    = (f32x4*)smem_raw;            // combine overlay, 9 f32x4/slot

  const int tid  = threadIdx.x;
  const int w    = tid >> 6;        // 0..7
  const int g    = w >> 2;          // K-group 0..1 (K=64 each)
  const int wl   = w & 3;           // wave-in-group
  const int lane = tid & 63;
  const int lane16 = lane & 15;
  const int quad   = lane >> 4;
  const int wm = wl >> 1;           // 64-row half
  const int wn = wl & 1;            // 64-col half

  // XCD-affine uniform mapping: 256 blocks = 16 panels x 16 ct-pairs; XCD
  // x_=b&7 owns panels {x_, x_+8} (L2-resident). Every block = 128 rows x
  // ct-pair {31-ctp, ctp} run sequentially = 33 K-steps (uniform).
  const int b   = (int)blockIdx.x;
  const int x_  = b & 7;
  const int jj  = b >> 3;                 // 0..31 within XCD
  const int p_  = x_ + 8 * (jj & 1);      // 128-row panel 0..15
  const int ctp = jj >> 1;                // 0..15
  const int ct1 = 31 - ctp;               // phase 1 (big, >=16)
  const int ct2 = ctp;                    // phase 2
  const int m0  = p_ * 128;

  const int stride1 = 128 * (ct1 + 1) + 200;
  const int stride2 = 128 * (ct2 + 1) + 200;
  const int base2   = 8 * stride1;        // elems
  const int W1 = 3968 - 128 * ct1;
  const int W2 = 3968 - 128 * ct2;

  // A addressing: f32 row-major. Lane reads 32B at row (rowb + fm*16),
  // k = t*128 + g*64 + kk*32 + quad*8.
  const int gu = __builtin_amdgcn_readfirstlane(g);
  const int rowb = m0 + wm * 64 + lane16;
  const float* pxb[4];
  for (int fm = 0; fm < 4; ++fm)
    pxb[fm] = x + (size_t)(rowb + fm * 16) * KDIM + gu * 64 + quad * 8;

  // ---- prologue: stage BOTH B windows (wave w stages copy w of each) ----
  auto stageWin = [&](int base_e, int stride_e, int Wp) {
    const u16* src = krevs + w * KREV_STRIDE + Wp;
    char* dstb = smem_raw + (size_t)(base_e + w * stride_e) * 2;
    for (int c = 0; c * 512 < stride_e; ++c) {
      int idx = c * 512 + lane * 8;
      if (idx < stride_e)
        async_copy16(src + idx, dstb + (size_t)c * 1024);
    }
  };
  stageWin(0, stride1, W1);
  stageWin(base2, stride2, W2);
  asm volatile("s_waitcnt vmcnt(0)" ::: "memory");
  __builtin_amdgcn_s_barrier();
  asm volatile("" ::: "memory");

  // ---- one phase: barrier-free K loop; raw-f32 A prefetch + in-reg cvt ----
  auto runPhase = [&](int ctq, int base_e, int stride_q, int Wq) {
    const int n0q = ctq * 128;
    int boff[4];
    for (int fn = 0; fn < 4; ++fn) {
      int n_g = n0q + wn * 64 + fn * 16 + lane16;
      int s0  = 4095 - n_g + quad * 8;
      int a   = s0 & 7;
      boff[fn] = base_e + a * stride_q + (s0 - a + 8 - Wq);
    }
    f32x4 acc[4][4] = {};
    f32x4 rA[4][2], rB[4][2];           // raw f32 for (t+1, kk0/kk1)
    bf16x8 afA[4], afB[4], bvA[4], bvB[4];

    // phase prologue: load+convert t=0 fragments, first LDS kk
#pragma unroll
    for (int fm = 0; fm < 4; ++fm) {
      const f32x4* p0 = (const f32x4*)(pxb[fm]);
      rA[fm][0] = p0[0]; rA[fm][1] = p0[1];
      const f32x4* p1 = (const f32x4*)(pxb[fm] + 32);
      rB[fm][0] = p1[0]; rB[fm][1] = p1[1];
    }
#pragma unroll
    for (int fm = 0; fm < 4; ++fm) afA[fm] = cvt8(rA[fm][0], rA[fm][1]);
#pragma unroll
    for (int fm = 0; fm < 4; ++fm) afB[fm] = cvt8(rB[fm][0], rB[fm][1]);
#pragma unroll
    for (int fn = 0; fn < 4; ++fn)
      bvA[fn] = *(const bf16x8*)(&B_all[boff[fn] + g * 64]);   // t=0, kk=0

    for (int t = 0; ; ++t) {
      const int ks = t * 128 + g * 64;
      // issue raw A loads for t+1 (in flight across this whole step's MFMAs)
      if (t < ctq) {
#pragma unroll
        for (int fm = 0; fm < 4; ++fm) {
          const f32x4* p0 = (const f32x4*)(pxb[fm] + (t + 1) * 128);
          rA[fm][0] = p0[0]; rA[fm][1] = p0[1];
          const f32x4* p1 = (const f32x4*)(pxb[fm] + (t + 1) * 128 + 32);
          rB[fm][0] = p1[0]; rB[fm][1] = p1[1];
        }
      }
      // kk=0: prefetch bvB (kk=1), consume afA/bvA
#pragma unroll
      for (int fn = 0; fn < 4; ++fn)
        bvB[fn] = *(const bf16x8*)(&B_all[boff[fn] + ks + 32]);
#pragma unroll
      for (int fn = 0; fn < 4; ++fn)
#pragma unroll
        for (int fm = 0; fm < 4; ++fm)
          acc[fm][fn] = MFMA_BF16(afA[fm], bvA[fn], acc[fm][fn], 0, 0, 0);
      // kk=1: prefetch bvA (t+1, kk=0), consume afB/bvB
      if (t < ctq)
#pragma unroll
        for (int fn = 0; fn < 4; ++fn)
          bvA[fn] = *(const bf16x8*)(&B_all[boff[fn] + ks + 128]);
#pragma unroll
      for (int fn = 0; fn < 4; ++fn)
#pragma unroll
        for (int fm = 0; fm < 4; ++fm)
          acc[fm][fn] = MFMA_BF16(afB[fm], bvB[fn], acc[fm][fn], 0, 0, 0);
      if (t == ctq) break;
      // convert the arrived raws (compiler inserts counted vmcnt)
#pragma unroll
      for (int fm = 0; fm < 4; ++fm) afA[fm] = cvt8(rA[fm][0], rA[fm][1]);
#pragma unroll
      for (int fm = 0; fm < 4; ++fm) afB[fm] = cvt8(rB[fm][0], rB[fm][1]);
    }

    // combine (R13 verbatim): group1 -> group0 via LDS overlay in the
    // phase-1 B region (dead after phase-1 compute); fused add + store.
    const int j = tid & 255;
#pragma unroll
    for (int r = 0; r < 2; ++r) {
      __syncthreads();
      if (g == 1) {
        for (int fm2 = 0; fm2 < 2; ++fm2)
          for (int fn = 0; fn < 4; ++fn)
            ep[j * 9 + fm2 * 4 + fn] = acc[r * 2 + fm2][fn];
      }
      __syncthreads();
      if (g == 0) {
        for (int fm2 = 0; fm2 < 2; ++fm2)
          for (int fn = 0; fn < 4; ++fn) {
            f32x4 v = acc[r * 2 + fm2][fn];
            f32x4 o = ep[j * 9 + fm2 * 4 + fn];
            v[0] += o[0]; v[1] += o[1]; v[2] += o[2]; v[3] += o[3];
            int fm = r * 2 + fm2;
            int row_base = m0 + wm * 64 + fm * 16 + quad * 4;
            int col = n0q + wn * 64 + fn * 16 + lane16;
            for (int rr = 0; rr < 4; ++rr)
              out[(size_t)(row_base + rr) * NDIM + col] = v[rr];
          }
      }
    }
  };

  runPhase(ct1, 0, stride1, W1);       // big phase first (region >= 38016 B)
  runPhase(ct2, base2, stride2, W2);   // its window untouched by the overlay
}

extern "C" void kernel_launch(void* const* d_in, const int* in_sizes, int n_in,
                              void* d_out, int out_size, void* d_ws, size_t ws_size,
                              hipStream_t stream) {
  const float* x    = (const float*)d_in[0];
  const float* kern = (const float*)d_in[1];
  float* out = (float*)d_out;

  u16* krevs = (u16*)d_ws;   // 73728 B; ws has always provided >= this

  prep<<<18, 256, 0, stream>>>(kern, krevs);
  toeplitz_gemm<<<256, 512, 0, stream>>>(x, krevs, out);
}

// Round 14
// 117.554 us; speedup vs baseline: 1.6971x; 1.6971x over previous
//
#include <hip/hip_runtime.h>
#include <hip/hip_bf16.h>

// out[b,i] = sum_{j<=i} x[b,j] * kernel[i-j]   (causal Toeplitz matmul)
// M=2048, N=K=4096. f32 in/out, bf16 MFMA compute.
//
// R19 = R14 (best, 112.49us) + XCD-affine prep. R18 proved the tiled-bf16 A
// intermediate is essential (row-major f32 A-frags = 16 scattered 128B
// segments/wave -> TA/L2 request-rate collapse, 137us). R14's one remaining
// inefficiency: prep wrote xb panels from arbitrary XCDs, so the gemm's
// XCD-affine readers (XCD x owns panels {x,x+8}) missed to HBM on first
// touch of all 16MB (gemm FETCH 8.5MB). Now prep's conv blocks are remapped
// bijectively (x_=b&7, rr=b>>3, p=x_+8*(rr&1), chunk=rr>>1) so panel p is
// converted by 256 blocks running on XCD p&7: dirty lines stay in the local
// L2 (2MB/XCD <= 4MB), gemm first-touch becomes L2-hit. Coalescing identical
// (1KB contiguous per wave write). Gemm: R14 verbatim -- uniform 33-step
// ct-pair blocks, whole-window B LDS, barrier-free K loop, A in registers
// 1 step ahead, bv double-buffered 1 kk ahead.

typedef unsigned short u16;
typedef __attribute__((ext_vector_type(8))) short  bf16x8;
typedef __attribute__((ext_vector_type(8))) unsigned short u16x8;
typedef __attribute__((ext_vector_type(4))) float  f32x4;

#define KDIM 4096
#define NDIM 4096
#define MDIM 2048
#define KREV_STRIDE 4608                    // elems per shifted copy (global)
#define KREV_BYTES  (8 * KREV_STRIDE * 2)   // 73728

#define MFMA_BF16 __builtin_amdgcn_mfma_f32_16x16x32_bf16

static __device__ inline u16 f2bf(float f) {
  unsigned u = __builtin_bit_cast(unsigned, f);
  unsigned r = u + 0x7FFFu + ((u >> 16) & 1u);
  return (u16)(r >> 16);
}

static __device__ inline void async_copy16(const void* g, void* l) {
  __builtin_amdgcn_global_load_lds((const __attribute__((address_space(1))) void*)g,
                                   (__attribute__((address_space(3))) void*)l,
                                   16, 0, 0);
}

// Fused prep: blocks [0, conv_blocks) convert x->bf16 into the fragment-tiled
// layout; last 18 blocks build 8 shifted krev copies.
// Tiled layout: elem index = (rg*128 + kb)*512 + l*8 + e, the 8 elems e being
// x[row = rg*16 + (l&15)][k = kb*32 + (l>>4)*8 + e]. One wave's fragment load
// (fixed rg,kb; l=lane) is 1KB contiguous.
// XCD-affinity: conv block b -> panel p = (b&7) + 8*((b>>3)&1), chunk =
// b>>4; panel p's 1MB is written by 256 blocks all on XCD p&7, matching the
// gemm's reader mapping (XCD x reads panels {x, x+8}) -> first touch L2-hit.
__global__ __launch_bounds__(256) void prep(const float* __restrict__ x,
                                            const float* __restrict__ kern,
                                            u16* __restrict__ xb,
                                            u16* __restrict__ krevs,
                                            int conv_blocks) {
  int kblk = (int)blockIdx.x - conv_blocks;
  if (kblk >= 0) {
    int u = kblk * 256 + threadIdx.x;
    for (int a = 0; a < 8; ++a) {
      int t = u + a - 8;
      u16 v = 0;
      if (t >= 0 && t <= 4095) v = f2bf(kern[4095 - t]);
      krevs[a * KREV_STRIDE + u] = v;
    }
  } else {
    int bx    = (int)blockIdx.x;
    int x_    = bx & 7;
    int rr    = bx >> 3;                             // 0..511
    int p     = x_ + 8 * (rr & 1);                   // panel 0..15 (XCD x_)
    int chunk = rr >> 1;                             // 0..255 within panel
    unsigned tg  = (unsigned)p * 65536u + (unsigned)chunk * 256u + threadIdx.x;
    unsigned l   = tg & 63;
    unsigned kb  = (tg >> 6) & 127;
    unsigned rg  = tg >> 13;                         // 0..127
    unsigned row = rg * 16 + (l & 15);
    unsigned k   = kb * 32 + (l >> 4) * 8;
    const f32x4* pp = (const f32x4*)(x + (size_t)row * KDIM + k);
    f32x4 v0 = pp[0], v1 = pp[1];
    u16x8 r;
    r[0] = f2bf(v0[0]); r[1] = f2bf(v0[1]); r[2] = f2bf(v0[2]); r[3] = f2bf(v0[3]);
    r[4] = f2bf(v1[0]); r[5] = f2bf(v1[1]); r[6] = f2bf(v1[2]); r[7] = f2bf(v1[3]);
    *(u16x8*)(xb + (size_t)tg * 8) = r;              // coalesced 1KB/wave
  }
}

template <bool CONV>
__global__ __launch_bounds__(512, 4) void toeplitz_gemm(const void* __restrict__ Av,
                                                        const u16* __restrict__ krevs,
                                                        float* __restrict__ out) {
  // LDS: two B windows, 8 copies each. len1+len2 = 128*33+320 = 4544 elems;
  // stride = len+40 (== 8 mod 64); stride1+stride2 = 4624 const -> 73984 B.
  // Phase-1 region (>= 38016 B, dead after phase 1) hosts the 36864 B
  // combine overlay; phase-2 region stays intact.
  __shared__ __align__(16) char smem_raw[73984];
  u16*   B_all = (u16*)smem_raw;
  f32x4* ep    = (f32x4*)smem_raw;            // combine overlay, 9 f32x4 per slot

  const int tid  = threadIdx.x;
  const int w    = tid >> 6;        // 0..7
  const int g    = w >> 2;          // K-group 0..1
  const int wl   = w & 3;           // wave-in-group
  const int lane = tid & 63;
  const int lane16 = lane & 15;
  const int quad   = lane >> 4;
  const int wm = wl >> 1;           // 32-row half
  const int wn = wl & 1;            // 64-col half

  // XCD-affine uniform mapping (R13): XCD x_=b&7 owns panels {x_, x_+8};
  // every block = one 64-row tile x column pair {31-ctp, ctp} = 33 K-steps.
  const int b   = (int)blockIdx.x;
  const int x_  = b & 7;
  const int jj  = b >> 3;                 // 0..63 within XCD
  const int p_  = x_ + 8 * (jj & 1);      // full panel 0..15
  const int mt2 = p_ * 2 + ((jj >> 1) & 1); // 64-row tile 0..31
  const int ctp = jj >> 2;                // 0..15
  const int ct1 = 31 - ctp;               // phase 1 (big, >=16)
  const int ct2 = ctp;                    // phase 2
  const int m0  = mt2 * 64;

  const int len1 = 128 * (ct1 + 1) + 160, stride1 = len1 + 40;
  const int len2 = 128 * (ct2 + 1) + 160, stride2 = len2 + 40;
  const int base2 = 8 * stride1;          // elems
  const int W1 = 3968 - 128 * ct1;
  const int W2 = 3968 - 128 * ct2;

  // A addressing (R11): SGPR-ized; elem(fm,t,kk) =
  // (mt2*4 + wm*2 + fm)*65536 + g*1024 + t*2048 + kk*512 + lane*8.
  const int wmu = __builtin_amdgcn_readfirstlane(wm);
  const int gu  = __builtin_amdgcn_readfirstlane(g);
  const u16*   xb2 = (const u16*)Av;
  const float* xf  = (const float*)Av;
  int aoffs[2];
  for (int fm = 0; fm < 2; ++fm)
    aoffs[fm] = (mt2 * 4 + wmu * 2 + fm) * 65536 + gu * 1024 + lane * 8;
  const int rowb = m0 + wm * 32 + lane16;   // CONV source row base

  auto ldA = [&](int fm, int t, int kk) -> bf16x8 {
    return *(const bf16x8*)(xb2 + aoffs[fm] + t * 2048 + kk * 512);
  };
  auto ldAc = [&](int fm, int t, int kk) -> bf16x8 {
    const float* px = xf + (size_t)(rowb + fm * 16) * KDIM +
                      t * 128 + gu * 64 + kk * 32 + quad * 8;
    f32x4 v0 = *(const f32x4*)px, v1 = *(const f32x4*)(px + 4);
    u16x8 r;
    r[0]=f2bf(v0[0]); r[1]=f2bf(v0[1]); r[2]=f2bf(v0[2]); r[3]=f2bf(v0[3]);
    r[4]=f2bf(v1[0]); r[5]=f2bf(v1[1]); r[6]=f2bf(v1[2]); r[7]=f2bf(v1[3]);
    return __builtin_bit_cast(bf16x8, r);
  };

  // ---- prologue: stage BOTH B windows (wave w stages copy w) ----
  auto stageWin = [&](int base_e, int stride_e, int len_e, int Wp) {
    const u16* src = krevs + w * KREV_STRIDE + Wp;
    char* dstb = smem_raw + (size_t)(base_e + w * stride_e) * 2;
    for (int c = 0; c * 512 < len_e; ++c) {
      int idx = c * 512 + lane * 8;
      if (idx < len_e)
        async_copy16(src + idx, dstb + (size_t)c * 1024);
    }
  };
  stageWin(0, stride1, len1, W1);
  stageWin(base2, stride2, len2, W2);
  asm volatile("s_waitcnt vmcnt(0)" ::: "memory");
  __builtin_amdgcn_s_barrier();
  asm volatile("" ::: "memory");

  // ---- one phase: barrier-free, B-reads pipelined one kk ahead ----
  auto runPhase = [&](int ctq, int base_e, int stride_q, int Wq) {
    const int n0q = ctq * 128;
    int boff[4];
    for (int fn = 0; fn < 4; ++fn) {
      int n_g = n0q + wn * 64 + fn * 16 + lane16;
      int s0  = 4095 - n_g + quad * 8;
      int a   = s0 & 7;
      boff[fn] = base_e + a * stride_q + (s0 - a + 8 - Wq);
    }
    f32x4 acc[2][4] = {};

    if constexpr (!CONV) {
      bf16x8 afA[2], afB[2], bvA[4], bvB[4];
#pragma unroll
      for (int fm = 0; fm < 2; ++fm) afA[fm] = ldA(fm, 0, 0);
#pragma unroll
      for (int fm = 0; fm < 2; ++fm) afB[fm] = ldA(fm, 0, 1);
#pragma unroll
      for (int fn = 0; fn < 4; ++fn)
        bvA[fn] = *(const bf16x8*)(&B_all[boff[fn] + g * 64]);   // t=0, kk=0
      for (int t = 0; ; ++t) {
        const int ks = t * 128 + g * 64;
        // kk=0: prefetch bvB (kk=1), consume bvA
#pragma unroll
        for (int fn = 0; fn < 4; ++fn)
          bvB[fn] = *(const bf16x8*)(&B_all[boff[fn] + ks + 32]);
#pragma unroll
        for (int fn = 0; fn < 4; ++fn)
#pragma unroll
          for (int fm = 0; fm < 2; ++fm)
            acc[fm][fn] = MFMA_BF16(afA[fm], bvA[fn], acc[fm][fn], 0, 0, 0);
        if (t < ctq)
#pragma unroll
          for (int fm = 0; fm < 2; ++fm) afA[fm] = ldA(fm, t + 1, 0);
        // kk=1: prefetch bvA (t+1, kk=0), consume bvB
        if (t < ctq)
#pragma unroll
          for (int fn = 0; fn < 4; ++fn)
            bvA[fn] = *(const bf16x8*)(&B_all[boff[fn] + ks + 128]);
#pragma unroll
        for (int fn = 0; fn < 4; ++fn)
#pragma unroll
          for (int fm = 0; fm < 2; ++fm)
            acc[fm][fn] = MFMA_BF16(afB[fm], bvB[fn], acc[fm][fn], 0, 0, 0);
        if (t == ctq) break;
#pragma unroll
        for (int fm = 0; fm < 2; ++fm) afB[fm] = ldA(fm, t + 1, 1);
      }
    } else {
      for (int t = 0; t <= ctq; ++t) {
        const int ks = t * 128 + g * 64;
#pragma unroll
        for (int kk = 0; kk < 2; ++kk) {
          bf16x8 af[2];
#pragma unroll
          for (int fm = 0; fm < 2; ++fm) af[fm] = ldAc(fm, t, kk);
#pragma unroll
          for (int fn = 0; fn < 4; ++fn) {
            bf16x8 bv = *(const bf16x8*)(&B_all[boff[fn] + ks + kk * 32]);
#pragma unroll
            for (int fm = 0; fm < 2; ++fm)
              acc[fm][fn] = MFMA_BF16(af[fm], bv, acc[fm][fn], 0, 0, 0);
          }
        }
      }
    }

    // combine: group1 -> group0 via LDS overlay (phase-1 B region, now dead)
    const int j = tid & 255;
    __syncthreads();                       // all compute on this phase done
    if (g == 1) {
      for (int fm = 0; fm < 2; ++fm)
        for (int fn = 0; fn < 4; ++fn)
          ep[j * 9 + fm * 4 + fn] = acc[fm][fn];
    }
    __syncthreads();
    if (g == 0) {
      for (int fm = 0; fm < 2; ++fm)
        for (int fn = 0; fn < 4; ++fn) {
          f32x4 v = acc[fm][fn];
          f32x4 o = ep[j * 9 + fm * 4 + fn];
          v[0] += o[0]; v[1] += o[1]; v[2] += o[2]; v[3] += o[3];
          int row_base = m0 + wm * 32 + fm * 16 + quad * 4;
          int col = n0q + wn * 64 + fn * 16 + lane16;
          for (int r = 0; r < 4; ++r)
            out[(size_t)(row_base + r) * NDIM + col] = v[r];
        }
    }
  };

  runPhase(ct1, 0, stride1, W1);       // big phase first (region >= 38KB)
  runPhase(ct2, base2, stride2, W2);   // its window untouched by the overlay
}

extern "C" void kernel_launch(void* const* d_in, const int* in_sizes, int n_in,
                              void* d_out, int out_size, void* d_ws, size_t ws_size,
                              hipStream_t stream) {
  const float* x    = (const float*)d_in[0];
  const float* kern = (const float*)d_in[1];
  float* out = (float*)d_out;

  u16* krevs = (u16*)d_ws;
  u16* xb    = (u16*)((char*)d_ws + KREV_BYTES);
  const size_t need_fast = (size_t)KREV_BYTES + (size_t)MDIM * KDIM * 2;

  if (ws_size >= need_fast) {
    prep<<<4096 + 18, 256, 0, stream>>>(x, kern, xb, krevs, 4096);
    toeplitz_gemm<false><<<512, 512, 0, stream>>>(xb, krevs, out);
  } else {
    prep<<<18, 256, 0, stream>>>(x, kern, xb, krevs, 0);
    toeplitz_gemm<true><<<512, 512, 0, stream>>>(x, krevs, out);
  }
}

// Round 15
// 115.018 us; speedup vs baseline: 1.7346x; 1.0221x over previous
//
#include <hip/hip_runtime.h>
#include <hip/hip_bf16.h>

// out[b,i] = sum_{j<=i} x[b,j] * kernel[i-j]   (causal Toeplitz matmul)
// M=2048, N=K=4096. f32 in/out, bf16 MFMA compute.
//
// R20 = R14 (best, 112.49us) + 2-cluster-deep B prefetch. R19's prep remap
// regressed (scattered prep reads) -> reverted. R14's residual, quantified:
// wall 2545 cyc/CU-round vs port-busy 1790 -> ~750 cyc = B-read QUEUE latency
// (16 waves x 4 reads ~ 64-deep queue x 12 cyc ~ 770 cyc issue->data) while
// R14's 1-cluster-ahead prefetch covers only ~310-620. Now each bv quad is
// issued exactly 2 MFMA-clusters before use (cover ~1240 > 770): 4 named
// buffers bv0..bv3 = cluster mod 4, main loop unrolled over (even,odd) round
// pairs so all buffer indexing is compile-time (no scratch). End-of-phase
// prefetch overshoot reads <=112B past the window -> +512B LDS slack (74496B,
// still 2 blocks/CU). Live regs: <=3 bv quads (48) + af dbuf 16 + addr ~25 =
// ~90 arch + 32 AGPR acc = ~122 <= 128 -> no spill (falsifier: WRITE_SIZE).
// Everything else (prep linear, uniform 33-step ct-pair blocks, XCD panel
// affinity, whole-window B staging, barrier-free loop, combine/epilogue):
// R14 verbatim.

typedef unsigned short u16;
typedef __attribute__((ext_vector_type(8))) short  bf16x8;
typedef __attribute__((ext_vector_type(8))) unsigned short u16x8;
typedef __attribute__((ext_vector_type(4))) float  f32x4;

#define KDIM 4096
#define NDIM 4096
#define MDIM 2048
#define KREV_STRIDE 4608                    // elems per shifted copy (global)
#define KREV_BYTES  (8 * KREV_STRIDE * 2)   // 73728

#define MFMA_BF16 __builtin_amdgcn_mfma_f32_16x16x32_bf16

static __device__ inline u16 f2bf(float f) {
  unsigned u = __builtin_bit_cast(unsigned, f);
  unsigned r = u + 0x7FFFu + ((u >> 16) & 1u);
  return (u16)(r >> 16);
}

static __device__ inline void async_copy16(const void* g, void* l) {
  __builtin_amdgcn_global_load_lds((const __attribute__((address_space(1))) void*)g,
                                   (__attribute__((address_space(3))) void*)l,
                                   16, 0, 0);
}

// Fused prep (R14): blocks [0, conv_blocks) convert x->bf16 into the
// fragment-tiled layout; last 18 blocks build 8 shifted krev copies.
// Tiled layout: elem index = (rg*128 + kb)*512 + l*8 + e, the 8 elems e being
// x[row = rg*16 + (l&15)][k = kb*32 + (l>>4)*8 + e]. One wave's fragment load
// (fixed rg,kb; l=lane) is 1KB contiguous.
__global__ __launch_bounds__(256) void prep(const float* __restrict__ x,
                                            const float* __restrict__ kern,
                                            u16* __restrict__ xb,
                                            u16* __restrict__ krevs,
                                            int conv_blocks) {
  int kblk = (int)blockIdx.x - conv_blocks;
  if (kblk >= 0) {
    int u = kblk * 256 + threadIdx.x;
    for (int a = 0; a < 8; ++a) {
      int t = u + a - 8;
      u16 v = 0;
      if (t >= 0 && t <= 4095) v = f2bf(kern[4095 - t]);
      krevs[a * KREV_STRIDE + u] = v;
    }
  } else {
    unsigned tg  = blockIdx.x * 256 + threadIdx.x;   // 0..2048*4096/8-1
    unsigned l   = tg & 63;
    unsigned kb  = (tg >> 6) & 127;
    unsigned rg  = tg >> 13;                         // 0..127
    unsigned row = rg * 16 + (l & 15);
    unsigned k   = kb * 32 + (l >> 4) * 8;
    const f32x4* p = (const f32x4*)(x + (size_t)row * KDIM + k);
    f32x4 v0 = p[0], v1 = p[1];
    u16x8 r;
    r[0] = f2bf(v0[0]); r[1] = f2bf(v0[1]); r[2] = f2bf(v0[2]); r[3] = f2bf(v0[3]);
    r[4] = f2bf(v1[0]); r[5] = f2bf(v1[1]); r[6] = f2bf(v1[2]); r[7] = f2bf(v1[3]);
    *(u16x8*)(xb + (size_t)tg * 8) = r;              // coalesced 1KB/wave
  }
}

template <bool CONV>
__global__ __launch_bounds__(512, 4) void toeplitz_gemm(const void* __restrict__ Av,
                                                        const u16* __restrict__ krevs,
                                                        float* __restrict__ out) {
  // LDS: two B windows, 8 copies each. len1+len2 = 128*33+320 = 4544 elems;
  // stride = len+40 (== 8 mod 64); stride1+stride2 = 4624 const -> 73984 B,
  // +512 B slack for the depth-2 prefetch overshoot (<=112 B) = 74496 B.
  // Phase-1 region (>= 38016 B, dead after phase 1) hosts the 36864 B
  // combine overlay; phase-2 region stays intact.
  __shared__ __align__(16) char smem_raw[74496];
  u16*   B_all = (u16*)smem_raw;
  f32x4* ep    = (f32x4*)smem_raw;            // combine overlay, 9 f32x4 per slot

  const int tid  = threadIdx.x;
  const int w    = tid >> 6;        // 0..7
  const int g    = w >> 2;          // K-group 0..1
  const int wl   = w & 3;           // wave-in-group
  const int lane = tid & 63;
  const int lane16 = lane & 15;
  const int quad   = lane >> 4;
  const int wm = wl >> 1;           // 32-row half
  const int wn = wl & 1;            // 64-col half

  // XCD-affine uniform mapping (R13): XCD x_=b&7 owns panels {x_, x_+8};
  // every block = one 64-row tile x column pair {31-ctp, ctp} = 33 K-steps.
  const int b   = (int)blockIdx.x;
  const int x_  = b & 7;
  const int jj  = b >> 3;                 // 0..63 within XCD
  const int p_  = x_ + 8 * (jj & 1);      // full panel 0..15
  const int mt2 = p_ * 2 + ((jj >> 1) & 1); // 64-row tile 0..31
  const int ctp = jj >> 2;                // 0..15
  const int ct1 = 31 - ctp;               // phase 1 (big, >=16)
  const int ct2 = ctp;                    // phase 2
  const int m0  = mt2 * 64;

  const int len1 = 128 * (ct1 + 1) + 160, stride1 = len1 + 40;
  const int len2 = 128 * (ct2 + 1) + 160, stride2 = len2 + 40;
  const int base2 = 8 * stride1;          // elems
  const int W1 = 3968 - 128 * ct1;
  const int W2 = 3968 - 128 * ct2;

  // A addressing (R11): SGPR-ized; elem(fm,t,kk) =
  // (mt2*4 + wm*2 + fm)*65536 + g*1024 + t*2048 + kk*512 + lane*8.
  const int wmu = __builtin_amdgcn_readfirstlane(wm);
  const int gu  = __builtin_amdgcn_readfirstlane(g);
  const u16*   xb2 = (const u16*)Av;
  const float* xf  = (const float*)Av;
  int aoffs[2];
  for (int fm = 0; fm < 2; ++fm)
    aoffs[fm] = (mt2 * 4 + wmu * 2 + fm) * 65536 + gu * 1024 + lane * 8;
  const int rowb = m0 + wm * 32 + lane16;   // CONV source row base

  auto ldA = [&](int fm, int t, int kk) -> bf16x8 {
    return *(const bf16x8*)(xb2 + aoffs[fm] + t * 2048 + kk * 512);
  };
  auto ldAc = [&](int fm, int t, int kk) -> bf16x8 {
    const float* px = xf + (size_t)(rowb + fm * 16) * KDIM +
                      t * 128 + gu * 64 + kk * 32 + quad * 8;
    f32x4 v0 = *(const f32x4*)px, v1 = *(const f32x4*)(px + 4);
    u16x8 r;
    r[0]=f2bf(v0[0]); r[1]=f2bf(v0[1]); r[2]=f2bf(v0[2]); r[3]=f2bf(v0[3]);
    r[4]=f2bf(v1[0]); r[5]=f2bf(v1[1]); r[6]=f2bf(v1[2]); r[7]=f2bf(v1[3]);
    return __builtin_bit_cast(bf16x8, r);
  };

  // ---- prologue: stage BOTH B windows (wave w stages copy w) ----
  auto stageWin = [&](int base_e, int stride_e, int len_e, int Wp) {
    const u16* src = krevs + w * KREV_STRIDE + Wp;
    char* dstb = smem_raw + (size_t)(base_e + w * stride_e) * 2;
    for (int c = 0; c * 512 < len_e; ++c) {
      int idx = c * 512 + lane * 8;
      if (idx < len_e)
        async_copy16(src + idx, dstb + (size_t)c * 1024);
    }
  };
  stageWin(0, stride1, len1, W1);
  stageWin(base2, stride2, len2, W2);
  asm volatile("s_waitcnt vmcnt(0)" ::: "memory");
  __builtin_amdgcn_s_barrier();
  asm volatile("" ::: "memory");

  // ---- one phase: barrier-free; B-reads 2 clusters ahead (4 buffers) ----
  auto runPhase = [&](int ctq, int base_e, int stride_q, int Wq) {
    const int n0q = ctq * 128;
    int boff[4];
    for (int fn = 0; fn < 4; ++fn) {
      int n_g = n0q + wn * 64 + fn * 16 + lane16;
      int s0  = 4095 - n_g + quad * 8;
      int a   = s0 & 7;
      boff[fn] = base_e + a * stride_q + (s0 - a + 8 - Wq);
    }
    f32x4 acc[2][4] = {};

    if constexpr (!CONV) {
      bf16x8 afA[2], afB[2], bv0[4], bv1[4], bv2[4], bv3[4];
#pragma unroll
      for (int fm = 0; fm < 2; ++fm) afA[fm] = ldA(fm, 0, 0);
#pragma unroll
      for (int fm = 0; fm < 2; ++fm) afB[fm] = ldA(fm, 0, 1);
#pragma unroll
      for (int fn = 0; fn < 4; ++fn)
        bv0[fn] = *(const bf16x8*)(&B_all[boff[fn] + g * 64]);        // (0,0)
#pragma unroll
      for (int fn = 0; fn < 4; ++fn)
        bv1[fn] = *(const bf16x8*)(&B_all[boff[fn] + g * 64 + 32]);   // (0,1)
      for (int t = 0; ; t += 2) {
        // ---- even round t: consume bv0/bv1, issue (t+1,*) into bv2/bv3 ----
        {
          const int ks = t * 128 + g * 64;
#pragma unroll
          for (int fn = 0; fn < 4; ++fn)
            bv2[fn] = *(const bf16x8*)(&B_all[boff[fn] + ks + 128]);
#pragma unroll
          for (int fn = 0; fn < 4; ++fn)
#pragma unroll
            for (int fm = 0; fm < 2; ++fm)
              acc[fm][fn] = MFMA_BF16(afA[fm], bv0[fn], acc[fm][fn], 0, 0, 0);
          if (t < ctq)
#pragma unroll
            for (int fm = 0; fm < 2; ++fm) afA[fm] = ldA(fm, t + 1, 0);
#pragma unroll
          for (int fn = 0; fn < 4; ++fn)
            bv3[fn] = *(const bf16x8*)(&B_all[boff[fn] + ks + 160]);
#pragma unroll
          for (int fn = 0; fn < 4; ++fn)
#pragma unroll
            for (int fm = 0; fm < 2; ++fm)
              acc[fm][fn] = MFMA_BF16(afB[fm], bv1[fn], acc[fm][fn], 0, 0, 0);
          if (t < ctq)
#pragma unroll
            for (int fm = 0; fm < 2; ++fm) afB[fm] = ldA(fm, t + 1, 1);
        }
        if (t == ctq) break;
        // ---- odd round t+1: consume bv2/bv3, issue (t+2,*) into bv0/bv1 ----
        {
          const int ks = (t + 1) * 128 + g * 64;
#pragma unroll
          for (int fn = 0; fn < 4; ++fn)
            bv0[fn] = *(const bf16x8*)(&B_all[boff[fn] + ks + 128]);
#pragma unroll
          for (int fn = 0; fn < 4; ++fn)
#pragma unroll
            for (int fm = 0; fm < 2; ++fm)
              acc[fm][fn] = MFMA_BF16(afA[fm], bv2[fn], acc[fm][fn], 0, 0, 0);
          if (t + 1 < ctq)
#pragma unroll
            for (int fm = 0; fm < 2; ++fm) afA[fm] = ldA(fm, t + 2, 0);
#pragma unroll
          for (int fn = 0; fn < 4; ++fn)
            bv1[fn] = *(const bf16x8*)(&B_all[boff[fn] + ks + 160]);
#pragma unroll
          for (int fn = 0; fn < 4; ++fn)
#pragma unroll
            for (int fm = 0; fm < 2; ++fm)
              acc[fm][fn] = MFMA_BF16(afB[fm], bv3[fn], acc[fm][fn], 0, 0, 0);
          if (t + 1 < ctq)
#pragma unroll
            for (int fm = 0; fm < 2; ++fm) afB[fm] = ldA(fm, t + 2, 1);
        }
        if (t + 1 == ctq) break;
      }
    } else {
      for (int t = 0; t <= ctq; ++t) {
        const int ks = t * 128 + g * 64;
#pragma unroll
        for (int kk = 0; kk < 2; ++kk) {
          bf16x8 af[2];
#pragma unroll
          for (int fm = 0; fm < 2; ++fm) af[fm] = ldAc(fm, t, kk);
#pragma unroll
          for (int fn = 0; fn < 4; ++fn) {
            bf16x8 bv = *(const bf16x8*)(&B_all[boff[fn] + ks + kk * 32]);
#pragma unroll
            for (int fm = 0; fm < 2; ++fm)
              acc[fm][fn] = MFMA_BF16(af[fm], bv, acc[fm][fn], 0, 0, 0);
          }
        }
      }
    }

    // combine: group1 -> group0 via LDS overlay (phase-1 B region, now dead)
    const int j = tid & 255;
    __syncthreads();                       // all compute on this phase done
    if (g == 1) {
      for (int fm = 0; fm < 2; ++fm)
        for (int fn = 0; fn < 4; ++fn)
          ep[j * 9 + fm * 4 + fn] = acc[fm][fn];
    }
    __syncthreads();
    if (g == 0) {
      for (int fm = 0; fm < 2; ++fm)
        for (int fn = 0; fn < 4; ++fn) {
          f32x4 v = acc[fm][fn];
          f32x4 o = ep[j * 9 + fm * 4 + fn];
          v[0] += o[0]; v[1] += o[1]; v[2] += o[2]; v[3] += o[3];
          int row_base = m0 + wm * 32 + fm * 16 + quad * 4;
          int col = n0q + wn * 64 + fn * 16 + lane16;
          for (int r = 0; r < 4; ++r)
            out[(size_t)(row_base + r) * NDIM + col] = v[r];
        }
    }
  };

  runPhase(ct1, 0, stride1, W1);       // big phase first (region >= 38KB)
  runPhase(ct2, base2, stride2, W2);   // its window untouched by the overlay
}

extern "C" void kernel_launch(void* const* d_in, const int* in_sizes, int n_in,
                              void* d_out, int out_size, void* d_ws, size_t ws_size,
                              hipStream_t stream) {
  const float* x    = (const float*)d_in[0];
  const float* kern = (const float*)d_in[1];
  float* out = (float*)d_out;

  u16* krevs = (u16*)d_ws;
  u16* xb    = (u16*)((char*)d_ws + KREV_BYTES);
  const size_t need_fast = (size_t)KREV_BYTES + (size_t)MDIM * KDIM * 2;

  if (ws_size >= need_fast) {
    prep<<<4096 + 18, 256, 0, stream>>>(x, kern, xb, krevs, 4096);
    toeplitz_gemm<false><<<512, 512, 0, stream>>>(xb, krevs, out);
  } else {
    prep<<<18, 256, 0, stream>>>(x, kern, xb, krevs, 0);
    toeplitz_gemm<true><<<512, 512, 0, stream>>>(x, krevs, out);
  }
}